// Round 15
// baseline (263.271 us; speedup 1.0000x reference)
//
#include <hip/hip_runtime.h>
#include <hip/hip_bf16.h>
#include <cstdint>

// GateAttention, restructured:
//   xcW|G1 = xc @ [WC | V_top]   (relu on xcW half; G1 bf16 -> ws)
//   xqW|xqVT = xq @ [WQ | V_bot] (relu on xqW half; V-half written transposed)
//   attn: S = xcW.xqW^T, softmax+mask -> P (global); O = P @ xqV;
//         out = sigmoid(G1 + O)
// Round 15: attn split into attn_qk (proven QK schedule, P -> global, reuses
// dead xcB buffer) and attn_pv (LDS-free, 1024x32-row blocks, 2 blocks/CU --
// the memory-bound PV/out phase finally gets latency-hiding parallelism).
// B=16, LC=2048, LQ=256, D=768, F=768.

using bf16 = __hip_bfloat16;
typedef __attribute__((ext_vector_type(8))) __bf16 bf16x8;
typedef __attribute__((ext_vector_type(4))) float f32x4;

typedef __attribute__((address_space(1))) const uint32_t GU32;
typedef __attribute__((address_space(3))) uint32_t LU32;

__device__ __forceinline__ void gll16(const bf16* g, bf16* l) {
  __builtin_amdgcn_global_load_lds((GU32*)g, (LU32*)l, 16, 0, 0);
}
__device__ __forceinline__ f32x4 mfma_bf16(bf16x8 a, bf16x8 b, f32x4 c) {
  return __builtin_amdgcn_mfma_f32_16x16x32_bf16(a, b, c, 0, 0, 0);
}
__device__ __forceinline__ bf16x8 ld_frag(const bf16* p) {
  return *reinterpret_cast<const bf16x8*>(p);
}
// LDS chunk swizzle (4 chunks of 16B per 64B row)
__device__ __forceinline__ int swz(int r) { return (r & 3) ^ ((r >> 2) & 1); }

__device__ __forceinline__ unsigned short f2bf_bits(float x) {
  bf16 b = __float2bfloat16(x);
  union { bf16 b; unsigned short s; } u;
  u.b = b;
  return u.s;
}

// ---------- fused prelude: 4 weight transposes + 2 input converts ----------
__global__ __launch_bounds__(256) void prep(
    const float* __restrict__ WC, const float* __restrict__ WQ,
    const float* __restrict__ V, const float* __restrict__ x_cont,
    const float* __restrict__ x_ques,
    bf16* __restrict__ Wct, bf16* __restrict__ Wqt,
    bf16* __restrict__ xcB, bf16* __restrict__ xqB) {
  const int bid = blockIdx.x;
  const int tid = threadIdx.x;
  if (bid < 2304) {
    __shared__ float tile[32][33];
    const int z = bid / 576, t = bid % 576;
    const float* in = (z == 0) ? WC : (z == 1) ? WQ : (z == 2) ? V : V + (long)768 * 768;
    bf16* out = (z == 0) ? Wct : (z == 1) ? Wqt
              : (z == 2) ? Wct + (long)768 * 768 : Wqt + (long)768 * 768;
    const int c0 = (t % 24) * 32, r0 = (t / 24) * 32;
    const int tx = tid & 31, ty = tid >> 5;
#pragma unroll
    for (int i = ty; i < 32; i += 8)
      tile[i][tx] = in[(long)(r0 + i) * 768 + (c0 + tx)];
    __syncthreads();
#pragma unroll
    for (int i = ty; i < 32; i += 8)
      out[(long)(c0 + i) * 768 + (r0 + tx)] = __float2bfloat16(tile[tx][i]);
  } else if (bid < 5376) {
    long i = (long)(bid - 2304) * 256 + tid;
#pragma unroll
    for (int k = 0; k < 8; ++k, i += 786432) {
      float4 v = reinterpret_cast<const float4*>(x_cont)[i];
      ushort4 o;
      o.x = f2bf_bits(v.x); o.y = f2bf_bits(v.y);
      o.z = f2bf_bits(v.z); o.w = f2bf_bits(v.w);
      reinterpret_cast<ushort4*>(xcB)[i] = o;
    }
  } else {
    long i = (long)(bid - 5376) * 256 + tid;
#pragma unroll
    for (int k = 0; k < 4; ++k, i += 196608) {
      float4 v = reinterpret_cast<const float4*>(x_ques)[i];
      ushort4 o;
      o.x = f2bf_bits(v.x); o.y = f2bf_bits(v.y);
      o.z = f2bf_bits(v.z); o.w = f2bf_bits(v.w);
      reinterpret_cast<ushort4*>(xqB)[i] = o;
    }
  }
}

// ---------- 128x128 GEMM, split epilogue (xq projection) -------------------
__global__ __launch_bounds__(256) void gemm_bt_split(
    const bf16* __restrict__ A, long lda,
    const bf16* __restrict__ Bt, long ldb,
    bf16* __restrict__ O1, bf16* __restrict__ O2t, int K) {
  __shared__ __align__(16) bf16 As[128 * 32];
  __shared__ __align__(16) bf16 Bs[128 * 32];
  const int tid = threadIdx.x;
  const int wave = tid >> 6;
  const int lane = tid & 63;
  const int l16 = lane & 15;
  const int kh = lane >> 4;
  const int wm = (wave >> 1) * 64;
  const int wn = (wave & 1) * 64;
  const long row0 = (long)blockIdx.x * 128;
  const long col0 = (long)blockIdx.y * 128;
  const int srow = tid >> 2;
  const int scol = ((tid & 3) ^ swz(srow)) * 8;

  const bf16* ap0 = A + (row0 + srow) * lda + scol;
  const bf16* ap1 = ap0 + 64 * lda;
  const bf16* bp0 = Bt + (col0 + srow) * ldb + scol;
  const bf16* bp1 = bp0 + 64 * ldb;
  bf16* as0 = As + wave * 512;
  bf16* as1 = as0 + 2048;
  bf16* bs0 = Bs + wave * 512;
  bf16* bs1 = bs0 + 2048;

  const int xc = (kh ^ swz(l16)) * 8;
  f32x4 acc[4][4] = {};

  for (int k0 = 0; k0 < K; k0 += 32) {
    gll16(ap0 + k0, as0);
    gll16(ap1 + k0, as1);
    gll16(bp0 + k0, bs0);
    gll16(bp1 + k0, bs1);
    __syncthreads();
    bf16x8 af[4], bfr[4];
#pragma unroll
    for (int i = 0; i < 4; ++i)
      af[i] = ld_frag(As + (wm + i * 16 + l16) * 32 + xc);
#pragma unroll
    for (int j = 0; j < 4; ++j)
      bfr[j] = ld_frag(Bs + (wn + j * 16 + l16) * 32 + xc);
#pragma unroll
    for (int i = 0; i < 4; ++i)
#pragma unroll
      for (int j = 0; j < 4; ++j)
        acc[i][j] = mfma_bf16(af[i], bfr[j], acc[i][j]);
    __syncthreads();
  }

  const bool isO1 = col0 < 768;
#pragma unroll
  for (int i = 0; i < 4; ++i)
#pragma unroll
    for (int j = 0; j < 4; ++j) {
      const long rowb = row0 + wm + i * 16 + kh * 4;
      const long col = col0 + wn + j * 16 + l16;
      if (isO1) {
#pragma unroll
        for (int r = 0; r < 4; ++r)
          O1[(rowb + r) * 768 + col] = __float2bfloat16(fmaxf(acc[i][j][r], 0.0f));
      } else {
        const int d = (int)(col - 768);
        const int b2 = (int)(rowb >> 8);
        const int q = (int)(rowb & 255);
        ushort4 u;
        u.x = f2bf_bits(acc[i][j][0]);
        u.y = f2bf_bits(acc[i][j][1]);
        u.z = f2bf_bits(acc[i][j][2]);
        u.w = f2bf_bits(acc[i][j][3]);
        *reinterpret_cast<ushort4*>(O2t + ((long)b2 * 768 + d) * 256 + q) = u;
      }
    }
}

// ---------- 256x256 GEMM, BK=32, 4 bufs, depth-3, ONE barrier/tile ---------
__global__ __launch_bounds__(512, 2) void gemm4b(
    const bf16* __restrict__ A, long lda,
    const bf16* __restrict__ Bt, long ldb,
    bf16* __restrict__ O1, bf16* __restrict__ O2, int K) {
  extern __shared__ __align__(16) bf16 smem[];
  const int tid = threadIdx.x;
  const int wid = tid >> 6;
  const int lane = tid & 63;
  const int l15 = lane & 15;
  const int g = lane >> 4;
  const int wm = wid >> 2;
  const int wn = wid & 3;

  const int lin = blockIdx.x;          // 0..767
  const int per = (int)gridDim.x >> 3; // 96
  const int wgid = (lin & 7) * per + (lin >> 3);
  const long row0 = (long)(wgid / 6) * 256;
  const long col0 = (long)(wgid % 6) * 256;

  const int srow = lane >> 2;
  const int sc = ((lane & 3) ^ swz(srow)) * 8;
  const int w16 = wid * 16;
  const bf16* Ab = A + (row0 + srow) * lda + sc;
  const bf16* Bb = Bt + (col0 + srow) * ldb + sc;

  f32x4 acc[8][4] = {};

  auto stageA = [&](int buf, int kk) {
    bf16* d = smem + buf * 16384 + w16 * 32;
    gll16(Ab + (long)w16 * lda + kk, d);
    gll16(Ab + (long)(128 + w16) * lda + kk, d + 128 * 32);
  };
  auto stageB = [&](int buf, int kk) {
    bf16* d = smem + buf * 16384 + 8192 + w16 * 32;
    gll16(Bb + (long)w16 * ldb + kk, d);
    gll16(Bb + (long)(128 + w16) * ldb + kk, d + 128 * 32);
  };
  const int xc = (g ^ swz(l15)) * 8;
  auto ldA = [&](int buf, int m) {
    int row = wm * 128 + m * 16 + l15;
    return ld_frag(smem + buf * 16384 + row * 32 + xc);
  };
  auto ldB = [&](int buf, int n) {
    int row = wn * 64 + n * 16 + l15;
    return ld_frag(smem + buf * 16384 + 8192 + row * 32 + xc);
  };

  stageA(0, 0);
  stageB(0, 0);
  stageA(1, 32);
  stageB(1, 32);
  stageA(2, 64);
  stageB(2, 64);

  const int NT = K >> 5;  // 24
  bf16x8 av[4], bv[4];

  for (int t = 0; t < NT; ++t) {
    const int cur = t & 3;

    if (t <= NT - 3)
      asm volatile("s_waitcnt vmcnt(8)\n\ts_barrier" ::: "memory");
    else if (t == NT - 2)
      asm volatile("s_waitcnt vmcnt(4)\n\ts_barrier" ::: "memory");
    else
      asm volatile("s_waitcnt vmcnt(0)\n\ts_barrier" ::: "memory");

    if (t + 3 < NT) {
      stageA((t + 3) & 3, (t + 3) << 5);
      stageB((t + 3) & 3, (t + 3) << 5);
    }

#pragma unroll
    for (int n = 0; n < 4; ++n) bv[n] = ldB(cur, n);
#pragma unroll
    for (int m = 0; m < 4; ++m) av[m] = ldA(cur, m);
    __builtin_amdgcn_s_setprio(1);
#pragma unroll
    for (int m = 0; m < 4; ++m)
#pragma unroll
      for (int n = 0; n < 4; ++n) acc[m][n] = mfma_bf16(av[m], bv[n], acc[m][n]);
    __builtin_amdgcn_s_setprio(0);

#pragma unroll
    for (int m = 0; m < 4; ++m) av[m] = ldA(cur, 4 + m);
    __builtin_amdgcn_s_setprio(1);
#pragma unroll
    for (int m = 0; m < 4; ++m)
#pragma unroll
      for (int n = 0; n < 4; ++n)
        acc[4 + m][n] = mfma_bf16(av[m], bv[n], acc[4 + m][n]);
    __builtin_amdgcn_s_setprio(0);
  }

  const bool isO1 = col0 < 768;
#pragma unroll
  for (int m = 0; m < 8; ++m)
#pragma unroll
    for (int n = 0; n < 4; ++n)
#pragma unroll
      for (int r = 0; r < 4; ++r) {
        long row = row0 + wm * 128 + m * 16 + g * 4 + r;
        long col = col0 + wn * 64 + n * 16 + l15;
        float v = acc[m][n][r];
        if (isO1)
          O1[row * 768 + col] = __float2bfloat16(fmaxf(v, 0.0f));
        else
          O2[row * 768 + (col - 768)] = __float2bfloat16(v);
      }
}

// ---------- attn_qk: S = xcW.xqW^T, softmax+mask -> P (global bf16) --------
// QK: 4 bufs, depth-3, ONE barrier/tile (vmcnt(6) ledger). Grid 256.
// LDS: bufs 96KB + wred/wsum 4KB = 100352 B.
__global__ __launch_bounds__(512) void attn_qk(
    const bf16* __restrict__ xcW, const bf16* __restrict__ xqW,
    const int* __restrict__ qlen_arr, bf16* __restrict__ Pg) {
  extern __shared__ __align__(16) bf16 smem[];
  float* wred = (float*)(smem + 49152);    // [128][4]
  float* wsum = wred + 512;                // [128][4]

  const int lin = blockIdx.x;     // 0..255
  const int xcd = lin & 7;
  const int jj = lin >> 3;        // 0..31
  const int b = xcd * 2 + (jj >> 4);
  const int ct = jj & 15;

  const int tid = threadIdx.x;
  const int wid = tid >> 6;
  const int lane = tid & 63;
  const int l16 = lane & 15;
  const int kh = lane >> 4;
  const int wm = wid >> 2;   // 0..1
  const int wn = wid & 3;    // 0..3

  const long crow0 = (long)b * 2048 + (long)ct * 128;
  const int srow = lane >> 2;
  const int sc = ((lane & 3) ^ swz(srow)) * 8;
  const int xcr = (kh ^ swz(l16)) * 8;

  const bf16* ap = xcW + (crow0 + wid * 16 + srow) * 768 + sc;
  const bf16* bp = xqW + ((long)b * 256 + wid * 32 + srow) * 768 + sc;
  const bf16* bp2 = bp + 16 * 768;

  auto stage = [&](int buf, int k0) {
    gll16(ap + k0, smem + buf * 12288 + wid * 512);
    bf16* bd = smem + buf * 12288 + 4096 + wid * 1024;
    gll16(bp + k0, bd);
    gll16(bp2 + k0, bd + 512);
  };

  f32x4 acc[4][4] = {};
  stage(0, 0);
  stage(1, 32);
  stage(2, 64);

  for (int t = 0; t < 24; ++t) {
    const int cur = t & 3;

    if (t <= 21)
      asm volatile("s_waitcnt vmcnt(6)\n\ts_barrier" ::: "memory");
    else if (t == 22)
      asm volatile("s_waitcnt vmcnt(3)\n\ts_barrier" ::: "memory");
    else
      asm volatile("s_waitcnt vmcnt(0)\n\ts_barrier" ::: "memory");

    if (t + 3 < 24) stage((t + 3) & 3, (t + 3) * 32);

    const bf16* Ac = smem + cur * 12288;
    const bf16* Bc = Ac + 4096;
    bf16x8 af[4], bfr[4];
#pragma unroll
    for (int i = 0; i < 4; ++i)
      af[i] = ld_frag(Ac + (wm * 64 + i * 16 + l16) * 32 + xcr);
#pragma unroll
    for (int j = 0; j < 4; ++j)
      bfr[j] = ld_frag(Bc + (wn * 64 + j * 16 + l16) * 32 + xcr);
    __builtin_amdgcn_s_setprio(1);
#pragma unroll
    for (int i = 0; i < 4; ++i)
#pragma unroll
      for (int j = 0; j < 4; ++j)
        acc[i][j] = mfma_bf16(af[i], bfr[j], acc[i][j]);
    __builtin_amdgcn_s_setprio(0);
  }

  const float scale = 0.036084391824351615f;  // 1/sqrt(768)
  const int qlen = qlen_arr[b];

#pragma unroll
  for (int i = 0; i < 4; ++i)
#pragma unroll
    for (int j = 0; j < 4; ++j) {
      int col = wn * 64 + j * 16 + l16;
      float m = (col >= qlen) ? -1.0e12f : 0.0f;
#pragma unroll
      for (int r = 0; r < 4; ++r)
        acc[i][j][r] = acc[i][j][r] * scale + m;
    }

#pragma unroll
  for (int i = 0; i < 4; ++i)
#pragma unroll
    for (int r = 0; r < 4; ++r) {
      float mx = fmaxf(fmaxf(acc[i][0][r], acc[i][1][r]),
                       fmaxf(acc[i][2][r], acc[i][3][r]));
      mx = fmaxf(mx, __shfl_xor(mx, 1));
      mx = fmaxf(mx, __shfl_xor(mx, 2));
      mx = fmaxf(mx, __shfl_xor(mx, 4));
      mx = fmaxf(mx, __shfl_xor(mx, 8));
      if (l16 == 0) wred[(wm * 64 + i * 16 + kh * 4 + r) * 4 + wn] = mx;
    }
  __syncthreads();

#pragma unroll
  for (int i = 0; i < 4; ++i)
#pragma unroll
    for (int r = 0; r < 4; ++r) {
      int row = wm * 64 + i * 16 + kh * 4 + r;
      float gm = fmaxf(fmaxf(wred[row * 4 + 0], wred[row * 4 + 1]),
                       fmaxf(wred[row * 4 + 2], wred[row * 4 + 3]));
      float s = 0.0f;
#pragma unroll
      for (int j = 0; j < 4; ++j) {
        float e = __expf(acc[i][j][r] - gm);
        acc[i][j][r] = e;
        s += e;
      }
      s += __shfl_xor(s, 1);
      s += __shfl_xor(s, 2);
      s += __shfl_xor(s, 4);
      s += __shfl_xor(s, 8);
      if (l16 == 0) wsum[row * 4 + wn] = s;
    }
  __syncthreads();

  // normalize and store P straight to global (bf16)
#pragma unroll
  for (int i = 0; i < 4; ++i)
#pragma unroll
    for (int r = 0; r < 4; ++r) {
      int row = wm * 64 + i * 16 + kh * 4 + r;
      float inv = 1.0f / (wsum[row * 4 + 0] + wsum[row * 4 + 1] +
                          wsum[row * 4 + 2] + wsum[row * 4 + 3]);
#pragma unroll
      for (int j = 0; j < 4; ++j)
        Pg[(crow0 + row) * 256 + wn * 64 + j * 16 + l16] =
            __float2bfloat16(acc[i][j][r] * inv);
    }
}

// ---------- attn_pv: O = P @ xqV ; out = sigmoid(G1 + O) -------------------
// LDS-free. 1024 blocks x 32 rows x 768 cols; 4 waves (wave = 32x192).
// P / xqVT / G1 are L2-hot per-XCD; 2 blocks/CU co-residency hides latency.
__global__ __launch_bounds__(256) void attn_pv(
    const bf16* __restrict__ Pg, const bf16* __restrict__ xqVT,
    const bf16* __restrict__ G1, float* __restrict__ out) {
  const int lin = blockIdx.x;     // 0..1023
  const int xcd = lin & 7;
  const int j7 = lin >> 3;        // 0..127
  const int b = xcd * 2 + (j7 >> 6);
  const int ct = j7 & 63;         // 32-row tiles

  const int tid = threadIdx.x;
  const int wn = tid >> 6;        // 0..3 -> 192 cols each
  const int lane = tid & 63;
  const int l16 = lane & 15;
  const int kh = lane >> 4;

  const long row0 = (long)b * 2048 + (long)ct * 32;
  const bf16* prow = Pg + row0 * 256;

  // hoist all P fragments (rows 0..31, k 0..255)
  bf16x8 pf[2][8];
#pragma unroll
  for (int m = 0; m < 2; ++m)
#pragma unroll
    for (int kk = 0; kk < 8; ++kk)
      pf[m][kk] = ld_frag(prow + (m * 16 + l16) * 256 + kk * 32 + kh * 8);

  const bf16* vb = xqVT + ((long)b * 768 + wn * 192 + l16) * 256;
  f32x4 acc[2][12] = {};

#pragma unroll
  for (int kk = 0; kk < 8; ++kk) {
    bf16x8 vf[12];
#pragma unroll
    for (int j = 0; j < 12; ++j)
      vf[j] = ld_frag(vb + (long)j * 16 * 256 + kk * 32 + kh * 8);
#pragma unroll
    for (int m = 0; m < 2; ++m)
#pragma unroll
      for (int j = 0; j < 12; ++j)
        acc[m][j] = mfma_bf16(pf[m][kk], vf[j], acc[m][j]);
  }

#pragma unroll
  for (int m = 0; m < 2; ++m)
#pragma unroll
    for (int j = 0; j < 12; ++j)
#pragma unroll
      for (int r = 0; r < 4; ++r) {
        long row = row0 + m * 16 + kh * 4 + r;
        int col = wn * 192 + j * 16 + l16;
        float v = acc[m][j][r] + __bfloat162float(G1[row * 768 + col]);
        out[row * 768 + col] = 1.0f / (1.0f + __expf(-v));
      }
}

extern "C" void kernel_launch(void* const* d_in, const int* in_sizes, int n_in,
                              void* d_out, int out_size, void* d_ws, size_t ws_size,
                              hipStream_t stream) {
  const float* x_cont = (const float*)d_in[0];  // [16,2048,768]
  const float* x_ques = (const float*)d_in[1];  // [16,256,768]
  const int* ques_len = (const int*)d_in[2];    // [16]
  const float* WC = (const float*)d_in[3];      // [768,768]
  const float* WQ = (const float*)d_in[4];      // [768,768]
  const float* V = (const float*)d_in[5];       // [1536,768]
  float* out = (float*)d_out;                   // [32768,768] f32

  // ws layout (bf16 elements)
  bf16* Wct = (bf16*)d_ws;                       // [1536][768] = [WC^T ; Vtop^T]
  bf16* Wqt = Wct + (long)1536 * 768;            // [1536][768] = [WQ^T ; Vbot^T]
  bf16* xcB = Wqt + (long)1536 * 768;            // [32768][768]
  bf16* xqB = xcB + (long)32768 * 768;           // [4096][768]
  bf16* xcW = xqB + (long)4096 * 768;            // [32768][768]
  bf16* xqW = xcW + (long)32768 * 768;           // [4096][768]
  bf16* xqVT = xqW + (long)4096 * 768;           // [16][768][256]
  bf16* G1 = xqVT + (long)16 * 768 * 256;        // [32768][768]
  bf16* Pg = xcB;                                // [32768][256] overlays dead xcB

  (void)hipFuncSetAttribute(reinterpret_cast<const void*>(&gemm4b),
                            hipFuncAttributeMaxDynamicSharedMemorySize, 131072);
  (void)hipFuncSetAttribute(reinterpret_cast<const void*>(&attn_qk),
                            hipFuncAttributeMaxDynamicSharedMemorySize, 102400);

  // fused prelude: weight transposes + input converts
  prep<<<6144, 256, 0, stream>>>(WC, WQ, V, x_cont, x_ques, Wct, Wqt, xcB, xqB);

  // xq fused projection: [xqW | xqVT] = relu/id(xq @ [WQ | Vbot]), V-half transposed
  gemm_bt_split<<<dim3(32, 12), 256, 0, stream>>>(xqB, 768, Wqt, 768, xqW, xqVT, 768);

  // xc fused projection: xcW (relu bf16) + G1 (bf16)
  gemm4b<<<768, 512, 131072, stream>>>(xcB, 768, Wct, 768, xcW, G1, 768);

  // attention: QK+softmax -> P (global, overlays xcB which is now dead)
  attn_qk<<<256, 512, 102400, stream>>>(xcW, xqW, ques_len, Pg);

  // PV + gate epilogue
  attn_pv<<<1024, 256, 0, stream>>>(Pg, xqVT, G1, out);
}

// Round 16
// 229.279 us; speedup vs baseline: 1.1483x; 1.1483x over previous
//
#include <hip/hip_runtime.h>
#include <hip/hip_bf16.h>
#include <cstdint>

// GateAttention, restructured (FINAL = round-14 configuration, 230.2us):
//   xcW|G1 = xc @ [WC | V_top]   (relu on xcW half; G1 bf16 -> ws)
//   xqW|xqVT = xq @ [WQ | V_bot] (relu on xqW half; V-half written transposed)
//   attn: S = xcW.xqW^T, softmax+mask, O = P @ xqV, out = sigmoid(G1 + O)
// Proven pieces: fused prep (BW-bound ~6TB/s); gemm4b 256^2/BK32/4-buf/
// depth-3/one-barrier-per-tile (103us, 31% MfmaUtil -- robust optimum across
// 6 structural variants); attn3 with one-barrier QK, P-in-LDS overlay,
// hoisted P and G1 fragments (rounds 8/9/11/15 alternatives all slower).
// B=16, LC=2048, LQ=256, D=768, F=768.

using bf16 = __hip_bfloat16;
typedef __attribute__((ext_vector_type(8))) __bf16 bf16x8;
typedef __attribute__((ext_vector_type(4))) float f32x4;

typedef __attribute__((address_space(1))) const uint32_t GU32;
typedef __attribute__((address_space(3))) uint32_t LU32;

__device__ __forceinline__ void gll16(const bf16* g, bf16* l) {
  __builtin_amdgcn_global_load_lds((GU32*)g, (LU32*)l, 16, 0, 0);
}
__device__ __forceinline__ f32x4 mfma_bf16(bf16x8 a, bf16x8 b, f32x4 c) {
  return __builtin_amdgcn_mfma_f32_16x16x32_bf16(a, b, c, 0, 0, 0);
}
__device__ __forceinline__ bf16x8 ld_frag(const bf16* p) {
  return *reinterpret_cast<const bf16x8*>(p);
}
// LDS chunk swizzle (4 chunks of 16B per 64B row)
__device__ __forceinline__ int swz(int r) { return (r & 3) ^ ((r >> 2) & 1); }

__device__ __forceinline__ unsigned short f2bf_bits(float x) {
  bf16 b = __float2bfloat16(x);
  union { bf16 b; unsigned short s; } u;
  u.b = b;
  return u.s;
}

// ---------- fused prelude: 4 weight transposes + 2 input converts ----------
// blocks [0,2304): transpose f32 [768][768] -> bf16 ^T (4 tasks x 576)
// blocks [2304,5376): x_cont f32 -> bf16 (3072 blocks x 8 quads/thread)
// blocks [5376,6144): x_ques f32 -> bf16 (768 blocks x 4 quads/thread)
__global__ __launch_bounds__(256) void prep(
    const float* __restrict__ WC, const float* __restrict__ WQ,
    const float* __restrict__ V, const float* __restrict__ x_cont,
    const float* __restrict__ x_ques,
    bf16* __restrict__ Wct, bf16* __restrict__ Wqt,
    bf16* __restrict__ xcB, bf16* __restrict__ xqB) {
  const int bid = blockIdx.x;
  const int tid = threadIdx.x;
  if (bid < 2304) {
    __shared__ float tile[32][33];
    const int z = bid / 576, t = bid % 576;
    const float* in = (z == 0) ? WC : (z == 1) ? WQ : (z == 2) ? V : V + (long)768 * 768;
    bf16* out = (z == 0) ? Wct : (z == 1) ? Wqt
              : (z == 2) ? Wct + (long)768 * 768 : Wqt + (long)768 * 768;
    const int c0 = (t % 24) * 32, r0 = (t / 24) * 32;
    const int tx = tid & 31, ty = tid >> 5;
#pragma unroll
    for (int i = ty; i < 32; i += 8)
      tile[i][tx] = in[(long)(r0 + i) * 768 + (c0 + tx)];
    __syncthreads();
#pragma unroll
    for (int i = ty; i < 32; i += 8)
      out[(long)(c0 + i) * 768 + (r0 + tx)] = __float2bfloat16(tile[tx][i]);
  } else if (bid < 5376) {
    long i = (long)(bid - 2304) * 256 + tid;   // 786432 threads, 8 iters
#pragma unroll
    for (int k = 0; k < 8; ++k, i += 786432) {
      float4 v = reinterpret_cast<const float4*>(x_cont)[i];
      ushort4 o;
      o.x = f2bf_bits(v.x); o.y = f2bf_bits(v.y);
      o.z = f2bf_bits(v.z); o.w = f2bf_bits(v.w);
      reinterpret_cast<ushort4*>(xcB)[i] = o;
    }
  } else {
    long i = (long)(bid - 5376) * 256 + tid;   // 196608 threads, 4 iters
#pragma unroll
    for (int k = 0; k < 4; ++k, i += 196608) {
      float4 v = reinterpret_cast<const float4*>(x_ques)[i];
      ushort4 o;
      o.x = f2bf_bits(v.x); o.y = f2bf_bits(v.y);
      o.z = f2bf_bits(v.z); o.w = f2bf_bits(v.w);
      reinterpret_cast<ushort4*>(xqB)[i] = o;
    }
  }
}

// ---------- 128x128 GEMM, split epilogue (xq projection) -------------------
// cols [0,768): relu -> xqW [4096][768] bf16.
// cols [768,1536): plain -> xqVT [16][768][256] bf16, written TRANSPOSED.
__global__ __launch_bounds__(256) void gemm_bt_split(
    const bf16* __restrict__ A, long lda,
    const bf16* __restrict__ Bt, long ldb,
    bf16* __restrict__ O1, bf16* __restrict__ O2t, int K) {
  __shared__ __align__(16) bf16 As[128 * 32];
  __shared__ __align__(16) bf16 Bs[128 * 32];
  const int tid = threadIdx.x;
  const int wave = tid >> 6;
  const int lane = tid & 63;
  const int l16 = lane & 15;
  const int kh = lane >> 4;
  const int wm = (wave >> 1) * 64;
  const int wn = (wave & 1) * 64;
  const long row0 = (long)blockIdx.x * 128;
  const long col0 = (long)blockIdx.y * 128;
  const int srow = tid >> 2;
  const int scol = ((tid & 3) ^ swz(srow)) * 8;

  const bf16* ap0 = A + (row0 + srow) * lda + scol;
  const bf16* ap1 = ap0 + 64 * lda;
  const bf16* bp0 = Bt + (col0 + srow) * ldb + scol;
  const bf16* bp1 = bp0 + 64 * ldb;
  bf16* as0 = As + wave * 512;
  bf16* as1 = as0 + 2048;
  bf16* bs0 = Bs + wave * 512;
  bf16* bs1 = bs0 + 2048;

  const int xc = (kh ^ swz(l16)) * 8;
  f32x4 acc[4][4] = {};

  for (int k0 = 0; k0 < K; k0 += 32) {
    gll16(ap0 + k0, as0);
    gll16(ap1 + k0, as1);
    gll16(bp0 + k0, bs0);
    gll16(bp1 + k0, bs1);
    __syncthreads();
    bf16x8 af[4], bfr[4];
#pragma unroll
    for (int i = 0; i < 4; ++i)
      af[i] = ld_frag(As + (wm + i * 16 + l16) * 32 + xc);
#pragma unroll
    for (int j = 0; j < 4; ++j)
      bfr[j] = ld_frag(Bs + (wn + j * 16 + l16) * 32 + xc);
#pragma unroll
    for (int i = 0; i < 4; ++i)
#pragma unroll
      for (int j = 0; j < 4; ++j)
        acc[i][j] = mfma_bf16(af[i], bfr[j], acc[i][j]);
    __syncthreads();
  }

  const bool isO1 = col0 < 768;
#pragma unroll
  for (int i = 0; i < 4; ++i)
#pragma unroll
    for (int j = 0; j < 4; ++j) {
      const long rowb = row0 + wm + i * 16 + kh * 4;
      const long col = col0 + wn + j * 16 + l16;
      if (isO1) {
#pragma unroll
        for (int r = 0; r < 4; ++r)
          O1[(rowb + r) * 768 + col] = __float2bfloat16(fmaxf(acc[i][j][r], 0.0f));
      } else {
        const int d = (int)(col - 768);
        const int b2 = (int)(rowb >> 8);
        const int q = (int)(rowb & 255);
        ushort4 u;
        u.x = f2bf_bits(acc[i][j][0]);
        u.y = f2bf_bits(acc[i][j][1]);
        u.z = f2bf_bits(acc[i][j][2]);
        u.w = f2bf_bits(acc[i][j][3]);
        *reinterpret_cast<ushort4*>(O2t + ((long)b2 * 768 + d) * 256 + q) = u;
      }
    }
}

// ---------- 256x256 GEMM, BK=32, 4 bufs, depth-3, ONE barrier/tile ---------
// cols [0,768): relu -> O1 bf16 (xcW) ; cols [768,1536): plain -> O2 bf16 (G1).
__global__ __launch_bounds__(512, 2) void gemm4b(
    const bf16* __restrict__ A, long lda,
    const bf16* __restrict__ Bt, long ldb,
    bf16* __restrict__ O1, bf16* __restrict__ O2, int K) {
  extern __shared__ __align__(16) bf16 smem[];  // 4 bufs x (A 8192 + B 8192) bf16
  const int tid = threadIdx.x;
  const int wid = tid >> 6;
  const int lane = tid & 63;
  const int l15 = lane & 15;
  const int g = lane >> 4;
  const int wm = wid >> 2;
  const int wn = wid & 3;

  const int lin = blockIdx.x;          // 0..767
  const int per = (int)gridDim.x >> 3; // 96
  const int wgid = (lin & 7) * per + (lin >> 3);
  const long row0 = (long)(wgid / 6) * 256;
  const long col0 = (long)(wgid % 6) * 256;

  const int srow = lane >> 2;
  const int sc = ((lane & 3) ^ swz(srow)) * 8;
  const int w16 = wid * 16;
  const bf16* Ab = A + (row0 + srow) * lda + sc;
  const bf16* Bb = Bt + (col0 + srow) * ldb + sc;

  f32x4 acc[8][4] = {};

  auto stageA = [&](int buf, int kk) {
    bf16* d = smem + buf * 16384 + w16 * 32;
    gll16(Ab + (long)w16 * lda + kk, d);
    gll16(Ab + (long)(128 + w16) * lda + kk, d + 128 * 32);
  };
  auto stageB = [&](int buf, int kk) {
    bf16* d = smem + buf * 16384 + 8192 + w16 * 32;
    gll16(Bb + (long)w16 * ldb + kk, d);
    gll16(Bb + (long)(128 + w16) * ldb + kk, d + 128 * 32);
  };
  const int xc = (g ^ swz(l15)) * 8;
  auto ldA = [&](int buf, int m) {
    int row = wm * 128 + m * 16 + l15;
    return ld_frag(smem + buf * 16384 + row * 32 + xc);
  };
  auto ldB = [&](int buf, int n) {
    int row = wn * 64 + n * 16 + l15;
    return ld_frag(smem + buf * 16384 + 8192 + row * 32 + xc);
  };

  stageA(0, 0);
  stageB(0, 0);
  stageA(1, 32);
  stageB(1, 32);
  stageA(2, 64);
  stageB(2, 64);

  const int NT = K >> 5;  // 24
  bf16x8 av[4], bv[4];

  for (int t = 0; t < NT; ++t) {
    const int cur = t & 3;

    if (t <= NT - 3)
      asm volatile("s_waitcnt vmcnt(8)\n\ts_barrier" ::: "memory");
    else if (t == NT - 2)
      asm volatile("s_waitcnt vmcnt(4)\n\ts_barrier" ::: "memory");
    else
      asm volatile("s_waitcnt vmcnt(0)\n\ts_barrier" ::: "memory");

    if (t + 3 < NT) {
      stageA((t + 3) & 3, (t + 3) << 5);
      stageB((t + 3) & 3, (t + 3) << 5);
    }

#pragma unroll
    for (int n = 0; n < 4; ++n) bv[n] = ldB(cur, n);
#pragma unroll
    for (int m = 0; m < 4; ++m) av[m] = ldA(cur, m);
    __builtin_amdgcn_s_setprio(1);
#pragma unroll
    for (int m = 0; m < 4; ++m)
#pragma unroll
      for (int n = 0; n < 4; ++n) acc[m][n] = mfma_bf16(av[m], bv[n], acc[m][n]);
    __builtin_amdgcn_s_setprio(0);

#pragma unroll
    for (int m = 0; m < 4; ++m) av[m] = ldA(cur, 4 + m);
    __builtin_amdgcn_s_setprio(1);
#pragma unroll
    for (int m = 0; m < 4; ++m)
#pragma unroll
      for (int n = 0; n < 4; ++n)
        acc[4 + m][n] = mfma_bf16(av[m], bv[n], acc[4 + m][n]);
    __builtin_amdgcn_s_setprio(0);
  }

  const bool isO1 = col0 < 768;
#pragma unroll
  for (int m = 0; m < 8; ++m)
#pragma unroll
    for (int n = 0; n < 4; ++n)
#pragma unroll
      for (int r = 0; r < 4; ++r) {
        long row = row0 + wm * 128 + m * 16 + g * 4 + r;
        long col = col0 + wn * 64 + n * 16 + l15;
        float v = acc[m][n][r];
        if (isO1)
          O1[row * 768 + col] = __float2bfloat16(fmaxf(v, 0.0f));
        else
          O2[row * 768 + (col - 768)] = __float2bfloat16(v);
      }
}

// ---------- fused attention + gate: 128 c-rows x 256 q-cols, 8 waves -------
// QK: 4 bufs, depth-3, ONE barrier/tile (vmcnt(6) ledger). P[128][264]
// overlays bufs 0-2 post-QK. G1 loads hoisted above each nb's PV MFMA loop.
__global__ __launch_bounds__(512) void attn3(
    const bf16* __restrict__ xcW, const bf16* __restrict__ xqW,
    const bf16* __restrict__ xqVT, const bf16* __restrict__ G1,
    const int* __restrict__ qlen_arr, float* __restrict__ out) {
  extern __shared__ __align__(16) bf16 smem[];
  bf16* P = smem;                          // overlays bufs 0-2 post-QK
  float* wred = (float*)(smem + 49152);    // [128][4]
  float* wsum = wred + 512;                // [128][4]

  // XCD-chunked: XCD x serves batches 2x,2x+1 (16 row-tiles each)
  const int lin = blockIdx.x;     // 0..255
  const int xcd = lin & 7;
  const int jj = lin >> 3;        // 0..31
  const int b = xcd * 2 + (jj >> 4);
  const int ct = jj & 15;

  const int tid = threadIdx.x;
  const int wid = tid >> 6;
  const int lane = tid & 63;
  const int l16 = lane & 15;
  const int kh = lane >> 4;
  const int wm = wid >> 2;   // 0..1
  const int wn = wid & 3;    // 0..3

  const long crow0 = (long)b * 2048 + (long)ct * 128;
  const int srow = lane >> 2;
  const int sc = ((lane & 3) ^ swz(srow)) * 8;
  const int xcr = (kh ^ swz(l16)) * 8;

  const bf16* ap = xcW + (crow0 + wid * 16 + srow) * 768 + sc;
  const bf16* bp = xqW + ((long)b * 256 + wid * 32 + srow) * 768 + sc;
  const bf16* bp2 = bp + 16 * 768;

  auto stage = [&](int buf, int k0) {
    gll16(ap + k0, smem + buf * 12288 + wid * 512);
    bf16* bd = smem + buf * 12288 + 4096 + wid * 1024;
    gll16(bp + k0, bd);
    gll16(bp2 + k0, bd + 512);
  };

  f32x4 acc[4][4] = {};
  stage(0, 0);
  stage(1, 32);
  stage(2, 64);

  for (int t = 0; t < 24; ++t) {
    const int cur = t & 3;

    if (t <= 21)
      asm volatile("s_waitcnt vmcnt(6)\n\ts_barrier" ::: "memory");
    else if (t == 22)
      asm volatile("s_waitcnt vmcnt(3)\n\ts_barrier" ::: "memory");
    else
      asm volatile("s_waitcnt vmcnt(0)\n\ts_barrier" ::: "memory");

    if (t + 3 < 24) stage((t + 3) & 3, (t + 3) * 32);

    const bf16* Ac = smem + cur * 12288;
    const bf16* Bc = Ac + 4096;
    bf16x8 af[4], bfr[4];
#pragma unroll
    for (int i = 0; i < 4; ++i)
      af[i] = ld_frag(Ac + (wm * 64 + i * 16 + l16) * 32 + xcr);
#pragma unroll
    for (int j = 0; j < 4; ++j)
      bfr[j] = ld_frag(Bc + (wn * 64 + j * 16 + l16) * 32 + xcr);
    __builtin_amdgcn_s_setprio(1);
#pragma unroll
    for (int i = 0; i < 4; ++i)
#pragma unroll
      for (int j = 0; j < 4; ++j)
        acc[i][j] = mfma_bf16(af[i], bfr[j], acc[i][j]);
    __builtin_amdgcn_s_setprio(0);
  }

  const float scale = 0.036084391824351615f;  // 1/sqrt(768)
  const int qlen = qlen_arr[b];

#pragma unroll
  for (int i = 0; i < 4; ++i)
#pragma unroll
    for (int j = 0; j < 4; ++j) {
      int col = wn * 64 + j * 16 + l16;
      float m = (col >= qlen) ? -1.0e12f : 0.0f;
#pragma unroll
      for (int r = 0; r < 4; ++r)
        acc[i][j][r] = acc[i][j][r] * scale + m;
    }

#pragma unroll
  for (int i = 0; i < 4; ++i)
#pragma unroll
    for (int r = 0; r < 4; ++r) {
      float mx = fmaxf(fmaxf(acc[i][0][r], acc[i][1][r]),
                       fmaxf(acc[i][2][r], acc[i][3][r]));
      mx = fmaxf(mx, __shfl_xor(mx, 1));
      mx = fmaxf(mx, __shfl_xor(mx, 2));
      mx = fmaxf(mx, __shfl_xor(mx, 4));
      mx = fmaxf(mx, __shfl_xor(mx, 8));
      if (l16 == 0) wred[(wm * 64 + i * 16 + kh * 4 + r) * 4 + wn] = mx;
    }
  __syncthreads();

#pragma unroll
  for (int i = 0; i < 4; ++i)
#pragma unroll
    for (int r = 0; r < 4; ++r) {
      int row = wm * 64 + i * 16 + kh * 4 + r;
      float gm = fmaxf(fmaxf(wred[row * 4 + 0], wred[row * 4 + 1]),
                       fmaxf(wred[row * 4 + 2], wred[row * 4 + 3]));
      float s = 0.0f;
#pragma unroll
      for (int j = 0; j < 4; ++j) {
        float e = __expf(acc[i][j][r] - gm);
        acc[i][j][r] = e;
        s += e;
      }
      s += __shfl_xor(s, 1);
      s += __shfl_xor(s, 2);
      s += __shfl_xor(s, 4);
      s += __shfl_xor(s, 8);
      if (l16 == 0) wsum[row * 4 + wn] = s;
    }
  __syncthreads();  // also separates last QK ds_read from P overlay writes

#pragma unroll
  for (int i = 0; i < 4; ++i)
#pragma unroll
    for (int r = 0; r < 4; ++r) {
      int row = wm * 64 + i * 16 + kh * 4 + r;
      float inv = 1.0f / (wsum[row * 4 + 0] + wsum[row * 4 + 1] +
                          wsum[row * 4 + 2] + wsum[row * 4 + 3]);
#pragma unroll
      for (int j = 0; j < 4; ++j)
        P[row * 264 + wn * 64 + j * 16 + l16] = __float2bfloat16(acc[i][j][r] * inv);
    }
  __syncthreads();

  // hoist P fragments (reused across all 3 nb sweeps)
  bf16x8 pf[4][8];
#pragma unroll
  for (int i = 0; i < 4; ++i)
#pragma unroll
    for (int kk = 0; kk < 8; ++kk)
      pf[i][kk] = ld_frag(P + (wm * 64 + i * 16 + l16) * 264 + kk * 32 + kh * 8);

  for (int nb = 0; nb < 3; ++nb) {
    const int n0 = nb * 256 + wn * 64;
    const bf16* btp = xqVT + ((long)b * 768 + n0) * 256;

    // hoisted G1 loads: latency hides under the PV MFMA loop below
    bf16 g1b[4][4][4];
#pragma unroll
    for (int i = 0; i < 4; ++i)
#pragma unroll
      for (int r = 0; r < 4; ++r) {
        long row = crow0 + wm * 64 + i * 16 + kh * 4 + r;
#pragma unroll
        for (int j = 0; j < 4; ++j)
          g1b[i][j][r] = G1[row * 768 + n0 + j * 16 + l16];
      }

    f32x4 a2[4][4] = {};
#pragma unroll
    for (int kk = 0; kk < 8; ++kk) {
      bf16x8 vf[4];
#pragma unroll
      for (int j = 0; j < 4; ++j)
        vf[j] = ld_frag(btp + (j * 16 + l16) * 256 + kk * 32 + kh * 8);
#pragma unroll
      for (int i = 0; i < 4; ++i)
#pragma unroll
        for (int j = 0; j < 4; ++j)
          a2[i][j] = mfma_bf16(pf[i][kk], vf[j], a2[i][j]);
    }
#pragma unroll
    for (int i = 0; i < 4; ++i)
#pragma unroll
      for (int j = 0; j < 4; ++j)
#pragma unroll
        for (int r = 0; r < 4; ++r) {
          long row = crow0 + wm * 64 + i * 16 + kh * 4 + r;
          int col = n0 + j * 16 + l16;
          float v = a2[i][j][r] + __bfloat162float(g1b[i][j][r]);
          out[row * 768 + col] = 1.0f / (1.0f + __expf(-v));
        }
  }
}

extern "C" void kernel_launch(void* const* d_in, const int* in_sizes, int n_in,
                              void* d_out, int out_size, void* d_ws, size_t ws_size,
                              hipStream_t stream) {
  const float* x_cont = (const float*)d_in[0];  // [16,2048,768]
  const float* x_ques = (const float*)d_in[1];  // [16,256,768]
  const int* ques_len = (const int*)d_in[2];    // [16]
  const float* WC = (const float*)d_in[3];      // [768,768]
  const float* WQ = (const float*)d_in[4];      // [768,768]
  const float* V = (const float*)d_in[5];       // [1536,768]
  float* out = (float*)d_out;                   // [32768,768] f32

  // ws layout (bf16 elements)
  bf16* Wct = (bf16*)d_ws;                       // [1536][768] = [WC^T ; Vtop^T]
  bf16* Wqt = Wct + (long)1536 * 768;            // [1536][768] = [WQ^T ; Vbot^T]
  bf16* xcB = Wqt + (long)1536 * 768;            // [32768][768]
  bf16* xqB = xcB + (long)32768 * 768;           // [4096][768]
  bf16* xcW = xqB + (long)4096 * 768;            // [32768][768]
  bf16* xqW = xcW + (long)32768 * 768;           // [4096][768]
  bf16* xqVT = xqW + (long)4096 * 768;           // [16][768][256]
  bf16* G1 = xqVT + (long)16 * 768 * 256;        // [32768][768]

  (void)hipFuncSetAttribute(reinterpret_cast<const void*>(&gemm4b),
                            hipFuncAttributeMaxDynamicSharedMemorySize, 131072);
  (void)hipFuncSetAttribute(reinterpret_cast<const void*>(&attn3),
                            hipFuncAttributeMaxDynamicSharedMemorySize, 102400);

  // fused prelude: weight transposes + input converts
  prep<<<6144, 256, 0, stream>>>(WC, WQ, V, x_cont, x_ques, Wct, Wqt, xcB, xqB);

  // xq fused projection: [xqW | xqVT] = relu/id(xq @ [WQ | Vbot]), V-half transposed
  gemm_bt_split<<<dim3(32, 12), 256, 0, stream>>>(xqB, 768, Wqt, 768, xqW, xqVT, 768);

  // xc fused projection: xcW (relu bf16) + G1 (bf16)
  gemm4b<<<768, 512, 131072, stream>>>(xcB, 768, Wct, 768, xcW, G1, 768);

  // attention + gate epilogue
  attn3<<<256, 512, 102400, stream>>>(xcW, xqW, xqVT, G1, ques_len, out);
}